// Round 5
// baseline (297.345 us; speedup 1.0000x reference)
//
#include <hip/hip_runtime.h>

#define GA 1024   // atoms per graph
#define GF 32     // max frags per graph
#define VIRT 4    // ligand_virtual entity index
#define NG 4      // graphs per block in K1 (per-wave pipelined, barrier-free)
#define KG 16     // graphs per finalize block

typedef _Float16 half8 __attribute__((ext_vector_type(8)));
typedef float f32x4 __attribute__((ext_vector_type(4)));
typedef unsigned int uint4v __attribute__((ext_vector_type(4)));

// LDS layout (bytes) for K1 — ALL regions wave-private:
//  X rows: 4 comp-major f16 rows [x|y|z|1] of 1024 atoms, stride 2080
//          (wave w owns bytes [w*512, w*512+512) of each row)
//  keys:   u8[1024] (wave w owns [w*256, w*256+256))
#define XSTRIDE 2080
#define KOFF    (4 * XSTRIDE)          // 8320
#define LDSSZ   (KOFF + GA)            // 9344

__device__ __forceinline__ unsigned int h2(float a, float b) {
    const unsigned short lo = __builtin_bit_cast(unsigned short, (_Float16)a);
    const unsigned short hi = __builtin_bit_cast(unsigned short, (_Float16)b);
    return (unsigned int)lo | ((unsigned int)hi << 16);
}

// ---------------------------------------------------------------------------
// K1: barrier-free pipelined one-hot-MFMA accumulate.
//   - NG graphs per block; next graph's 6 global loads are issued BEFORE the
//     current sweep, so each wave's memory phase hides under compute (T14).
//   - ZERO barriers / __syncthreads: staging+keys are wave-private, so waves
//     drift out of phase and the CU never oscillates in lockstep (the theory
//     for the 2.7 TB/s plateau of rounds 0/1/2).
//   - fold: 16 lanes/wave do 8 global atomicAdd(f32) each into sums_cnt
//     (zeroed by host memset). Counts are integer-valued f32 -> order-exact.
//   - per-wave nfrag max -> plain stores to nfrag4[B*4]; k_fin folds.
// ---------------------------------------------------------------------------
__global__ __launch_bounds__(256, 8) void k_graph_acc(
    const float* __restrict__ pos,
    const int*   __restrict__ frag,
    const int*   __restrict__ entity,
    const int*   __restrict__ mask,
    float*       __restrict__ sums_cnt,   // [B*GF*4]  (pre-zeroed, atomic dst)
    int*         __restrict__ nfrag4,     // [B*4] per-wave raw maxes
    unsigned*    __restrict__ frag8u)     // [B*GA/4] s8 raw frag (may be null)
{
    const int t    = threadIdx.x;
    const int lane = t & 63;
    const int w    = t >> 6;
    const int g0   = blockIdx.x * NG;

    __shared__ alignas(16) unsigned char lds[LDSSZ];

    const int row = lane & 15;            // A row (slot) / D col (comp)
    const int grp = lane >> 4;            // k-octet selector
    const unsigned xo_l = (unsigned)((row & 3) * XSTRIDE + (w * 256 + grp * 8) * 2);
    const unsigned ko_l = (unsigned)(KOFF + w * 256 + grp * 8);

    // prologue: load graph g0 into prefetch regs
    int4 f4, e4, m4; float4 pa, pb, pc;
    {
        const size_t i0 = (size_t)g0 * GA + t * 4;
        f4 = *(const int4*)(frag   + i0);
        e4 = *(const int4*)(entity + i0);
        m4 = *(const int4*)(mask   + i0);
        const float4* p4 = (const float4*)(pos + 3 * i0);
        pa = p4[0]; pb = p4[1]; pc = p4[2];
    }

    #pragma unroll
    for (int it = 0; it < NG; ++it) {
        const int g = g0 + it;
        const int4  cf = f4, ce = e4, cm = m4;
        const float4 qa = pa, qb = pb, qc = pc;

        // issue next graph's loads NOW — they land during this sweep
        if (it + 1 < NG) {
            const size_t i0 = (size_t)(g + 1) * GA + t * 4;
            f4 = *(const int4*)(frag   + i0);
            e4 = *(const int4*)(entity + i0);
            m4 = *(const int4*)(mask   + i0);
            const float4* p4 = (const float4*)(pos + 3 * i0);
            pa = p4[0]; pb = p4[1]; pc = p4[2];
        }

        // compact raw-frag stash for k_fin (values in [-1,31] fit s8)
        if (frag8u) {
            const unsigned s8p = (cf.x & 0xFFu)         | ((cf.y & 0xFFu) << 8)
                               | ((cf.z & 0xFFu) << 16) | ((unsigned)(cf.w & 0xFFu) << 24);
            frag8u[(size_t)g * (GA / 4) + t] = s8p;
        }

        // stage keys (masked) — wave-private region
        #define KEYV(F,M,E) ((unsigned)(((F) >= 0 && (M) != 0 && (E) != VIRT) ? (unsigned)(F) : 0xFFu))
        const unsigned kp = KEYV(cf.x,cm.x,ce.x)        | (KEYV(cf.y,cm.y,ce.y) << 8)
                          | (KEYV(cf.z,cm.z,ce.z) << 16) | (KEYV(cf.w,cm.w,ce.w) << 24);
        *(unsigned*)(lds + KOFF + t * 4) = kp;
        #undef KEYV

        // stage positions comp-major f16 (+ const-1 row) — wave-private cols
        // atom0=(qa.x,qa.y,qa.z) atom1=(qa.w,qb.x,qb.y) atom2=(qb.z,qb.w,qc.x) atom3=(qc.y,qc.z,qc.w)
        *(uint2*)(lds + 0 * XSTRIDE + t * 8) = make_uint2(h2(qa.x, qa.w), h2(qb.z, qc.y)); // x
        *(uint2*)(lds + 1 * XSTRIDE + t * 8) = make_uint2(h2(qa.y, qb.x), h2(qb.w, qc.z)); // y
        *(uint2*)(lds + 2 * XSTRIDE + t * 8) = make_uint2(h2(qa.z, qb.y), h2(qc.x, qc.w)); // z
        *(uint2*)(lds + 3 * XSTRIDE + t * 8) = make_uint2(0x3C003C00u, 0x3C003C00u);       // 1.0h

        // nfrag: per-wave max over raw frag (mask/entity do NOT apply, per ref)
        int lm = max(max(cf.x, cf.y), max(cf.z, cf.w));
        #pragma unroll
        for (int off = 32; off > 0; off >>= 1)
            lm = max(lm, __shfl_down(lm, off, 64));
        if (lane == 0) nfrag4[g * 4 + w] = lm;

        // one-hot MFMA sweep over this wave's 256 atoms
        f32x4 acc0 = {0.f, 0.f, 0.f, 0.f};   // slots  0..15
        f32x4 acc1 = {0.f, 0.f, 0.f, 0.f};   // slots 16..31
        #pragma unroll
        for (int s = 0; s < 8; ++s) {
            const uint2  kk = *(const uint2*)(lds + ko_l + s * 32);   // 8 keys (16x bcast)
            const uint4v bv = *(const uint4v*)(lds + xo_l + s * 64);  // B frag: 8 f16
            uint4v a0, a1;
            #pragma unroll
            for (int p = 0; p < 4; ++p) {
                const unsigned word = (p & 2) ? kk.y : kk.x;
                const unsigned k0 = (word >> ((p & 1) * 16)) & 0xFFu;
                const unsigned k1 = (word >> ((p & 1) * 16 + 8)) & 0xFFu;
                a0[p] = (k0 == (unsigned)row        ? 0x3C00u : 0u)
                      | (k1 == (unsigned)row        ? 0x3C000000u : 0u);
                a1[p] = (k0 == (unsigned)(row + 16) ? 0x3C00u : 0u)
                      | (k1 == (unsigned)(row + 16) ? 0x3C000000u : 0u);
            }
            acc0 = __builtin_amdgcn_mfma_f32_16x16x32_f16(
                       __builtin_bit_cast(half8, a0), __builtin_bit_cast(half8, bv), acc0, 0, 0, 0);
            acc1 = __builtin_amdgcn_mfma_f32_16x16x32_f16(
                       __builtin_bit_cast(half8, a1), __builtin_bit_cast(half8, bv), acc1, 0, 0, 0);
        }

        // fold via global f32 atomics (no barrier, no LDS round-trip)
        // D layout (HW-verified): lane holds D[grp*4 + r][col = lane&15]
        if (row < 4) {
            float* dst = sums_cnt + (size_t)g * (GF * 4);
            #pragma unroll
            for (int r = 0; r < 4; ++r) {
                atomicAdd(dst + (grp * 4 + r) * 4 + row,        acc0[r]);
                atomicAdd(dst + (16 + grp * 4 + r) * 4 + row,   acc1[r]);
            }
        }
    }
}

// ---------------------------------------------------------------------------
// K2: finalize (round-4 proven). Each block redundantly computes the full
// exclusive scan of nfrag in LDS (no cross-block sync), then finalizes its
// KG graphs: coms/cnt, explicit zeroing of padding rows, flat from frag8.
// Changed: scan input is max of the 4 per-wave maxes in nfrag4 (+1).
// ---------------------------------------------------------------------------
__global__ __launch_bounds__(256) void k_fin(
    const int4*     __restrict__ nfrag4v,   // [B] int4 of per-wave maxes
    const float4*   __restrict__ sums_cnt,  // [B*GF]
    const unsigned* __restrict__ frag8u,    // [B*GA/4] or null
    const int4*     __restrict__ frag4,     // fallback if frag8u null
    float*          __restrict__ coms,      // [B*GF*3]
    float*          __restrict__ cnt_out,   // [B*GF]
    float4*         __restrict__ out4,      // [N/4]
    int B)
{
    const int b = blockIdx.x;
    const int t = threadIdx.x;
    const int C = B / 256;                  // 32 elements per thread
    __shared__ int s[8192 + 256];           // padded: addr = idx + idx/32
    __shared__ int ps[256];

    // ---- redundant exclusive scan of nfrag ----
    for (int k = 0; k < C; ++k) {
        const int idx = k * 256 + t;        // coalesced int4 loads
        const int4 nv = nfrag4v[idx];
        s[idx + (idx >> 5)] = max(max(nv.x, nv.y), max(nv.z, nv.w)) + 1;
    }
    __syncthreads();
    int sum = 0;
    for (int k = 0; k < C; ++k) {
        const int idx = t * C + k;
        const int p = idx + (idx >> 5);
        const int v = s[p];
        s[p] = sum;
        sum += v;
    }
    ps[t] = sum;
    __syncthreads();
    for (int d = 1; d < 256; d <<= 1) {
        const int v = (t >= d) ? ps[t - d] : 0;
        __syncthreads();
        ps[t] += v;
        __syncthreads();
    }
    #define OFF(g) (s[(g) + ((g) >> 5)] + (((g) >> 5) ? ps[((g) >> 5) - 1] : 0))
    const int total = ps[255];              // sum of all nfrag

    const int g0 = b * KG;

    // ---- coms/cnt: KG*GF entries, 32-thread group per graph ----
    #pragma unroll
    for (int k = 0; k < (KG * GF) / 256; ++k) {   // 2 iters
        const int e  = k * 256 + t;
        const int j  = e >> 5, fr = e & 31;
        const int g  = g0 + j;
        const int4 nv = nfrag4v[g];               // L1-broadcast
        const int nfr = max(max(nv.x, nv.y), max(nv.z, nv.w)) + 1;
        if (fr < nfr) {
            const float4 v = sums_cnt[(size_t)g * GF + fr];
            const int rr = OFF(g) + fr;
            const float inv = 1.0f / fmaxf(v.w, 1.0f);
            coms[3 * rr + 0] = v.x * inv;
            coms[3 * rr + 1] = v.y * inv;
            coms[3 * rr + 2] = v.z * inv;
            cnt_out[rr] = v.w;
        }
    }

    // ---- zero padding rows [total, B*GF): grid tiles 512 rows/block ----
    #pragma unroll
    for (int k = 0; k < 2; ++k) {
        const int r = b * 512 + k * 256 + t;      // covers [0, 262144) exactly
        if (r >= total) {
            coms[3 * r + 0] = 0.0f; coms[3 * r + 1] = 0.0f; coms[3 * r + 2] = 0.0f;
            cnt_out[r] = 0.0f;
        }
    }

    // ---- flat: KG graphs x 1024 atoms, coalesced float4 stores ----
    for (int j = 0; j < KG; ++j) {
        const int g = g0 + j;
        const float fo = (float)OFF(g);           // uniform per j
        float4 o;
        if (frag8u) {
            const unsigned kk = frag8u[(size_t)g * (GA / 4) + t];
            const int a0 = ((int)(kk << 24)) >> 24;
            const int a1 = ((int)(kk << 16)) >> 24;
            const int a2 = ((int)(kk <<  8)) >> 24;
            const int a3 = ((int)kk) >> 24;
            o.x = (a0 >= 0) ? (float)a0 + fo : -1.0f;
            o.y = (a1 >= 0) ? (float)a1 + fo : -1.0f;
            o.z = (a2 >= 0) ? (float)a2 + fo : -1.0f;
            o.w = (a3 >= 0) ? (float)a3 + fo : -1.0f;
        } else {
            const int4 f = frag4[(size_t)g * (GA / 4) + t];
            o.x = (f.x >= 0) ? (float)f.x + fo : -1.0f;
            o.y = (f.y >= 0) ? (float)f.y + fo : -1.0f;
            o.z = (f.z >= 0) ? (float)f.z + fo : -1.0f;
            o.w = (f.w >= 0) ? (float)f.w + fo : -1.0f;
        }
        out4[(size_t)g * (GA / 4) + t] = o;
    }
    #undef OFF
}

// ---------------------------------------------------------------------------
extern "C" void kernel_launch(void* const* d_in, const int* in_sizes, int n_in,
                              void* d_out, int out_size, void* d_ws, size_t ws_size,
                              hipStream_t stream)
{
    const float* pos    = (const float*)d_in[0];
    const int*   frag   = (const int*)d_in[1];
    // d_in[2] = batch_idx: unused, it's exactly i / 1024 (contiguous graphs)
    const int*   entity = (const int*)d_in[3];
    const int*   mask   = (const int*)d_in[4];   // bool passed as int32

    const int N = in_sizes[1];          // 8388608
    const int B = N / GA;               // 8192

    // workspace layout
    float*    sums_cnt = (float*)d_ws;                            // B*GF*4 floats
    int*      nfrag4   = (int*)(sums_cnt + (size_t)B * GF * 4);   // B*4 ints
    unsigned* frag8u   = (unsigned*)(nfrag4 + (size_t)B * 4);     // N bytes (optional)
    const size_t needed = (size_t)B * GF * 4 * 4 + (size_t)B * 16 + (size_t)N;
    if (ws_size < needed) frag8u = nullptr;   // k_fin falls back to frag re-read

    // output layout (all float32) — k_fin writes every element (incl. padding)
    float* coms     = (float*)d_out;                // B*GF*3
    float* cnt_out  = coms + (size_t)B * GF * 3;    // B*GF
    float* flat_out = cnt_out + (size_t)B * GF;     // N

    // zero the atomic accumulation buffer
    hipMemsetAsync(sums_cnt, 0, (size_t)B * GF * 4 * sizeof(float), stream);

    k_graph_acc<<<B / NG, 256, 0, stream>>>(pos, frag, entity, mask,
                                            sums_cnt, nfrag4, frag8u);

    k_fin<<<B / KG, 256, 0, stream>>>(
        (const int4*)nfrag4, (const float4*)sums_cnt, (const unsigned*)frag8u,
        (const int4*)frag, coms, cnt_out, (float4*)flat_out, B);
}

// Round 6
// 258.212 us; speedup vs baseline: 1.1516x; 1.1516x over previous
//
#include <hip/hip_runtime.h>

#define GA 1024   // atoms per graph
#define GF 32     // max frags per graph
#define VIRT 4    // ligand_virtual entity index

typedef _Float16 half8 __attribute__((ext_vector_type(8)));
typedef float f32x4 __attribute__((ext_vector_type(4)));
typedef unsigned int uint4v __attribute__((ext_vector_type(4)));

// LDS layout (bytes) for K1 (round-4 proven, 81us):
#define XSTRIDE 2080
#define KOFF    (4 * XSTRIDE)          // 8320
#define FOFF    (KOFF + GA)            // 9344
#define LDSSZ   (FOFF + 4 * GF * 4 * 4) // 11392

__device__ __forceinline__ unsigned int h2(float a, float b) {
    const unsigned short lo = __builtin_bit_cast(unsigned short, (_Float16)a);
    const unsigned short hi = __builtin_bit_cast(unsigned short, (_Float16)b);
    return (unsigned int)lo | ((unsigned int)hi << 16);
}

// ---------------------------------------------------------------------------
// K1: one block per graph (round-4 proven). One-hot MFMA segmented sum +
// compact frag8 stash. UNCHANGED from round 4 (81us) for clean attribution.
// ---------------------------------------------------------------------------
__global__ __launch_bounds__(256) void k_graph_acc(
    const float* __restrict__ pos,
    const int*   __restrict__ frag,
    const int*   __restrict__ entity,
    const int*   __restrict__ mask,
    float*       __restrict__ sums_cnt,   // [B*GF*4]  layout [f*4 + c]
    int*         __restrict__ nfrag,      // [B]
    unsigned*    __restrict__ frag8u)     // [B*GA/4] s8 raw frag
{
    const int g    = blockIdx.x;
    const int t    = threadIdx.x;
    const int lane = t & 63;
    const int w    = t >> 6;

    __shared__ alignas(16) unsigned char lds[LDSSZ];
    __shared__ int s_wmax[4];

    const int i0 = g * GA + t * 4;
    const int4  f4 = *(const int4*)(frag   + i0);
    const int4  e4 = *(const int4*)(entity + i0);
    const int4  m4 = *(const int4*)(mask   + i0);
    const float4* p4 = (const float4*)(pos + (size_t)3 * i0);
    const float4 pa = p4[0], pb = p4[1], pc = p4[2];
    // atom0=(pa.x,pa.y,pa.z) atom1=(pa.w,pb.x,pb.y) atom2=(pb.z,pb.w,pc.x) atom3=(pc.y,pc.z,pc.w)

    // compact raw-frag stash for k_fin2 (values in [-1,31] fit s8)
    const unsigned s8p = (f4.x & 0xFFu)         | ((f4.y & 0xFFu) << 8)
                       | ((f4.z & 0xFFu) << 16) | ((unsigned)(f4.w & 0xFFu) << 24);
    frag8u[(size_t)g * (GA / 4) + t] = s8p;

    #define KEY(F,M,E) ((unsigned)(((F) >= 0 && (M) != 0 && (E) != VIRT) ? (unsigned)(F) : 0xFFu))
    const unsigned kp = KEY(f4.x,m4.x,e4.x)        | (KEY(f4.y,m4.y,e4.y) << 8)
                      | (KEY(f4.z,m4.z,e4.z) << 16) | (KEY(f4.w,m4.w,e4.w) << 24);
    *(unsigned*)(lds + KOFF + t * 4) = kp;
    #undef KEY

    *(uint2*)(lds + 0 * XSTRIDE + t * 8) = make_uint2(h2(pa.x, pa.w), h2(pb.z, pc.y)); // x
    *(uint2*)(lds + 1 * XSTRIDE + t * 8) = make_uint2(h2(pa.y, pb.x), h2(pb.w, pc.z)); // y
    *(uint2*)(lds + 2 * XSTRIDE + t * 8) = make_uint2(h2(pa.z, pb.y), h2(pc.x, pc.w)); // z
    *(uint2*)(lds + 3 * XSTRIDE + t * 8) = make_uint2(0x3C003C00u, 0x3C003C00u);       // 1.0h

    // nfrag: max over raw frag (mask/entity do NOT apply, matching reference)
    int lm = max(max(f4.x, f4.y), max(f4.z, f4.w));
    #pragma unroll
    for (int off = 32; off > 0; off >>= 1)
        lm = max(lm, __shfl_down(lm, off, 64));
    if (lane == 0) s_wmax[w] = lm;

    // one-hot MFMA sweep over this wave's 256 atoms
    f32x4 acc0 = {0.f, 0.f, 0.f, 0.f};   // slots  0..15
    f32x4 acc1 = {0.f, 0.f, 0.f, 0.f};   // slots 16..31
    const int row = lane & 15;            // A row (slot) / D col (comp)
    const int grp = lane >> 4;            // k-octet selector
    const unsigned xoff = (unsigned)((row & 3) * XSTRIDE + (w * 256 + grp * 8) * 2);
    const unsigned koff = (unsigned)(KOFF + w * 256 + grp * 8);

    #pragma unroll
    for (int s = 0; s < 8; ++s) {
        const uint2  kk = *(const uint2*)(lds + koff + s * 32);   // 8 keys (16x bcast)
        const uint4v bv = *(const uint4v*)(lds + xoff + s * 64);  // B frag: 8 f16
        uint4v a0, a1;
        #pragma unroll
        for (int p = 0; p < 4; ++p) {
            const unsigned word = (p & 2) ? kk.y : kk.x;
            const unsigned k0 = (word >> ((p & 1) * 16)) & 0xFFu;
            const unsigned k1 = (word >> ((p & 1) * 16 + 8)) & 0xFFu;
            a0[p] = (k0 == (unsigned)row        ? 0x3C00u : 0u)
                  | (k1 == (unsigned)row        ? 0x3C000000u : 0u);
            a1[p] = (k0 == (unsigned)(row + 16) ? 0x3C00u : 0u)
                  | (k1 == (unsigned)(row + 16) ? 0x3C000000u : 0u);
        }
        acc0 = __builtin_amdgcn_mfma_f32_16x16x32_f16(
                   __builtin_bit_cast(half8, a0), __builtin_bit_cast(half8, bv), acc0, 0, 0, 0);
        acc1 = __builtin_amdgcn_mfma_f32_16x16x32_f16(
                   __builtin_bit_cast(half8, a1), __builtin_bit_cast(half8, bv), acc1, 0, 0, 0);
    }

    // fold 4 wave-partials
    // D layout (HW-verified): lane holds D[grp*4 + r][col = lane&15], col = comp
    float* fold = (float*)(lds + FOFF);
    if (row < 4) {
        #pragma unroll
        for (int r = 0; r < 4; ++r) {
            fold[(w * GF + grp * 4 + r) * 4 + row]      = acc0[r];
            fold[(w * GF + 16 + grp * 4 + r) * 4 + row] = acc1[r];
        }
    }
    __syncthreads();
    if (t < GF * 4) {
        const float v = fold[t] + fold[128 + t] + fold[256 + t] + fold[384 + t];
        sums_cnt[(size_t)g * (GF * 4) + t] = v;   // coalesced 512B store
    }
    if (t == 0)
        nfrag[g] = max(max(s_wmax[0], s_wmax[1]), max(s_wmax[2], s_wmax[3])) + 1;
}

// ---------------------------------------------------------------------------
// K2: single-block exclusive scan of nfrag[B] -> offset[B], plus
// offset[B] slot gets the grand total. (round-0 proven body)
// ---------------------------------------------------------------------------
__global__ __launch_bounds__(256) void k_scan(
    const int* __restrict__ nfrag, int* __restrict__ offset, int B)
{
    const int t = threadIdx.x;
    const int C = B / 256;                  // 32 elements per thread
    __shared__ int s[8192 + 256];           // padded: addr = idx + idx/32
    __shared__ int ps[256];

    for (int k = 0; k < C; ++k) {
        const int idx = k * 256 + t;        // coalesced
        s[idx + (idx >> 5)] = nfrag[idx];
    }
    __syncthreads();

    int sum = 0;
    for (int k = 0; k < C; ++k) {
        const int idx = t * C + k;
        const int p = idx + (idx >> 5);
        const int v = s[p];
        s[p] = sum;
        sum += v;
    }
    ps[t] = sum;
    __syncthreads();

    for (int d = 1; d < 256; d <<= 1) {
        const int v = (t >= d) ? ps[t - d] : 0;
        __syncthreads();
        ps[t] += v;
        __syncthreads();
    }

    for (int k = 0; k < C; ++k) {
        const int idx = k * 256 + t;        // coalesced
        const int c = idx >> 5;
        const int pre = (c == 0) ? 0 : ps[c - 1];
        offset[idx] = pre + s[idx + (idx >> 5)];
    }
    if (t == 255) offset[B] = ps[255];      // grand total
}

// ---------------------------------------------------------------------------
// K3: wide finalize. ONE BLOCK PER GRAPH (8192 blocks — vs round-4's 512 =
// 2/CU, which was latency/occupancy-bound). No LDS, no barriers:
//   all t : frag8 load (4B) -> flat float4 store
//   t<32  : coms/cnt row t from sums_cnt + offset[b] (scalar), and zero
//           padding row b*32+t if >= total (kills the memset)
// ---------------------------------------------------------------------------
__global__ __launch_bounds__(256) void k_fin2(
    const int*      __restrict__ nfrag,     // [B]
    const int*      __restrict__ offset,    // [B+1], offset[B] = total
    const float4*   __restrict__ sums_cnt,  // [B*GF]
    const unsigned* __restrict__ frag8u,    // [B*GA/4]
    float*          __restrict__ coms,      // [B*GF*3]
    float*          __restrict__ cnt_out,   // [B*GF]
    float4*         __restrict__ out4,      // [N/4]
    int B)
{
    const int b = blockIdx.x;
    const int t = threadIdx.x;
    const int off = offset[b];              // wave-uniform scalar

    // flat: 1024 atoms, coalesced
    {
        const float fo = (float)off;
        const unsigned kk = frag8u[(size_t)b * (GA / 4) + t];
        const int a0 = ((int)(kk << 24)) >> 24;
        const int a1 = ((int)(kk << 16)) >> 24;
        const int a2 = ((int)(kk <<  8)) >> 24;
        const int a3 = ((int)kk) >> 24;
        float4 o;
        o.x = (a0 >= 0) ? (float)a0 + fo : -1.0f;
        o.y = (a1 >= 0) ? (float)a1 + fo : -1.0f;
        o.z = (a2 >= 0) ? (float)a2 + fo : -1.0f;
        o.w = (a3 >= 0) ? (float)a3 + fo : -1.0f;
        out4[(size_t)b * (GA / 4) + t] = o;
    }

    if (t < GF) {
        // coms/cnt for this graph's row t
        if (t < nfrag[b]) {
            const float4 v = sums_cnt[(size_t)b * GF + t];
            const int rr = off + t;
            const float inv = 1.0f / fmaxf(v.w, 1.0f);
            coms[3 * rr + 0] = v.x * inv;
            coms[3 * rr + 1] = v.y * inv;
            coms[3 * rr + 2] = v.z * inv;
            cnt_out[rr] = v.w;
        }
        // zero padding rows: block b owns rows [b*32, b*32+32)
        const int r = b * GF + t;
        if (r >= offset[B]) {
            coms[3 * r + 0] = 0.0f; coms[3 * r + 1] = 0.0f; coms[3 * r + 2] = 0.0f;
            cnt_out[r] = 0.0f;
        }
    }
}

// ---------------------------------------------------------------------------
extern "C" void kernel_launch(void* const* d_in, const int* in_sizes, int n_in,
                              void* d_out, int out_size, void* d_ws, size_t ws_size,
                              hipStream_t stream)
{
    const float* pos    = (const float*)d_in[0];
    const int*   frag   = (const int*)d_in[1];
    // d_in[2] = batch_idx: unused, it's exactly i / 1024 (contiguous graphs)
    const int*   entity = (const int*)d_in[3];
    const int*   mask   = (const int*)d_in[4];   // bool passed as int32

    const int N = in_sizes[1];          // 8388608
    const int B = N / GA;               // 8192

    // workspace layout
    float*    sums_cnt = (float*)d_ws;                            // B*GF*4 floats
    int*      nfrag    = (int*)(sums_cnt + (size_t)B * GF * 4);   // B ints
    int*      offset   = nfrag + B;                               // B+1 ints
    unsigned* frag8u   = (unsigned*)(offset + B + 1);             // N bytes

    // output layout (all float32) — k_fin2 writes every element (incl. padding)
    float* coms     = (float*)d_out;                // B*GF*3
    float* cnt_out  = coms + (size_t)B * GF * 3;    // B*GF
    float* flat_out = cnt_out + (size_t)B * GF;     // N

    k_graph_acc<<<B, 256, 0, stream>>>(pos, frag, entity, mask,
                                       sums_cnt, nfrag, frag8u);

    k_scan<<<1, 256, 0, stream>>>(nfrag, offset, B);

    k_fin2<<<B, 256, 0, stream>>>(
        nfrag, offset, (const float4*)sums_cnt, (const unsigned*)frag8u,
        coms, cnt_out, (float4*)flat_out, B);
}